// Round 1
// baseline (318.479 us; speedup 1.0000x reference)
//
#include <hip/hip_runtime.h>
#include <math.h>

#define NUM_BINS 20
#define NACC     (3 * NUM_BINS)   // 60: [0,20) = sum w, [20,40) = sum w*p, [40,60) = sum w*t
#define BLOCK    256
#define NBLK_MAX 2048             // 256 CU x 8 blocks/CU x 4 waves = 8192 waves = 100% occupancy

// w_j(p) = exp(-(p - c_j)^2 / T) = exp2(K1*p*p) * exp2(K2*p)^j * exp2(K1*c_j*c_j)
//   K1 = -1/(T*ln2), K2 = 2/(19*T*ln2), T = 0.1, c_j = j/19
__device__ __host__ constexpr float K1f() { return (float)(-1.0 / (0.1 * 0.6931471805599453)); }
__device__ __host__ constexpr float K2f() { return (float)( 2.0 / (1.9 * 0.6931471805599453)); }

__global__ __launch_bounds__(BLOCK) void ace_partial(const float* __restrict__ p,
                                                     const float* __restrict__ t,
                                                     float* __restrict__ partials,
                                                     int n4) {
    const float K1 = K1f();
    const float K2 = K2f();

    float aW[NUM_BINS], aP[NUM_BINS], aT[NUM_BINS];
#pragma unroll
    for (int j = 0; j < NUM_BINS; ++j) { aW[j] = 0.f; aP[j] = 0.f; aT[j] = 0.f; }

    const float4* __restrict__ p4 = (const float4*)p;
    const float4* __restrict__ t4 = (const float4*)t;

    int tid    = blockIdx.x * BLOCK + threadIdx.x;
    int stride = gridDim.x * BLOCK;

    for (int i = tid; i < n4; i += stride) {
        float4 pv = p4[i];
        float4 tv = t4[i];

        float pe[4] = {pv.x, pv.y, pv.z, pv.w};
        float te[4] = {tv.x, tv.y, tv.z, tv.w};

#pragma unroll
        for (int e = 0; e < 4; ++e) {
            float pp = pe[e];
            float tt = te[e];
            float u  = __builtin_amdgcn_exp2f(K1 * pp * pp);  // exp(-p^2/T)
            float G  = __builtin_amdgcn_exp2f(K2 * pp);       // exp(2p/(19T))
            float g  = u;                                     // u * G^j, j=0
#pragma unroll
            for (int j = 0; j < NUM_BINS; ++j) {
                aW[j] += g;
                aP[j]  = fmaf(g, pp, aP[j]);
                aT[j]  = fmaf(g, tt, aT[j]);
                g     *= G;
            }
        }
    }

    // Wave(64)-level tree reduction of all 60 accumulators
#pragma unroll
    for (int j = 0; j < NUM_BINS; ++j) {
#pragma unroll
        for (int off = 32; off > 0; off >>= 1) {
            aW[j] += __shfl_down(aW[j], off, 64);
            aP[j] += __shfl_down(aP[j], off, 64);
            aT[j] += __shfl_down(aT[j], off, 64);
        }
    }

    __shared__ float red[BLOCK / 64][NACC];
    int wave = threadIdx.x >> 6;
    int lane = threadIdx.x & 63;
    if (lane == 0) {
#pragma unroll
        for (int j = 0; j < NUM_BINS; ++j) {
            red[wave][j]                = aW[j];
            red[wave][NUM_BINS + j]     = aP[j];
            red[wave][2 * NUM_BINS + j] = aT[j];
        }
    }
    __syncthreads();

    if (threadIdx.x < NACC) {
        float s = 0.f;
#pragma unroll
        for (int w = 0; w < BLOCK / 64; ++w) s += red[w][threadIdx.x];
        partials[blockIdx.x * NACC + threadIdx.x] = s;
    }
}

__global__ __launch_bounds__(1024) void ace_final(const float* __restrict__ partials,
                                                  float* __restrict__ out,
                                                  int nblk) {
    const float K1 = K1f();

    __shared__ float red[NACC][16];
    __shared__ float sums[NACC];
    int tid = threadIdx.x;

    if (tid < NACC * 16) {
        int j = tid >> 4;
        int k = tid & 15;
        float s = 0.f;
        for (int b = k; b < nblk; b += 16) s += partials[b * NACC + j];
        red[j][k] = s;
    }
    __syncthreads();

    if (tid < NACC) {
        float s = 0.f;
#pragma unroll
        for (int k = 0; k < 16; ++k) s += red[tid][k];
        sums[tid] = s;
    }
    __syncthreads();

    if (tid == 0) {
        float acc = 0.f;
        for (int j = 0; j < NUM_BINS; ++j) {
            float c    = (float)j / 19.0f;
            float A    = __builtin_amdgcn_exp2f(K1 * c * c);  // exp(-c^2/T)
            float wsum = A * sums[j];
            float denom = wsum + 1e-8f;
            float e    = (A * sums[NUM_BINS + j]) / denom;
            float o    = (A * sums[2 * NUM_BINS + j]) / denom;
            float contrib = (wsum == 0.0f) ? 0.0f : fabsf(e - o);
            acc += contrib;
        }
        out[0] = acc / (float)NUM_BINS;
    }
}

extern "C" void kernel_launch(void* const* d_in, const int* in_sizes, int n_in,
                              void* d_out, int out_size, void* d_ws, size_t ws_size,
                              hipStream_t stream) {
    const float* preds   = (const float*)d_in[0];
    const float* targets = (const float*)d_in[1];
    float* out           = (float*)d_out;
    float* partials      = (float*)d_ws;

    int n  = in_sizes[0];
    int n4 = n >> 2;   // N = 32*1024*1024, divisible by 4

    // Fill the machine: 2048 blocks x 4 waves = 8192 waves = 32 waves/CU on 256 CUs.
    // Clamp against workspace in case ws_size < NBLK_MAX * NACC * 4 bytes.
    int nblk = NBLK_MAX;
    size_t need = (size_t)nblk * NACC * sizeof(float);
    if (ws_size < need) {
        nblk = (int)(ws_size / (NACC * sizeof(float)));
        if (nblk > 1024) nblk = 1024;   // keep a sane fallback geometry
        if (nblk < 1)    nblk = 1;
    }

    ace_partial<<<nblk, BLOCK, 0, stream>>>(preds, targets, partials, n4);
    ace_final<<<1, 1024, 0, stream>>>(partials, out, nblk);
}

// Round 2
// 300.806 us; speedup vs baseline: 1.0588x; 1.0588x over previous
//
#include <hip/hip_runtime.h>
#include <math.h>

#define NUM_BINS 20
#define NPAIR    (NUM_BINS / 2)    // bins packed in adjacent pairs (2j, 2j+1)
#define NACC     (3 * NUM_BINS)    // 60 scalar accumulators total
#define BLOCK    256
#define NBLK     1024              // 1024 blocks x 4 waves = 4096 waves = 4/SIMD (reg-capped anyway)

typedef float v2f __attribute__((ext_vector_type(2)));

// w_j(p) = exp(-(p - c_j)^2 / T) = exp2(K1*p*p) * exp2(K2*p)^j * exp2(K1*c_j*c_j)
//   K1 = -1/(T*ln2), K2 = 2/(19*T*ln2), T = 0.1, c_j = j/19
__device__ __host__ constexpr float K1f() { return (float)(-1.0 / (0.1 * 0.6931471805599453)); }
__device__ __host__ constexpr float K2f() { return (float)( 2.0 / (1.9 * 0.6931471805599453)); }

__global__ __launch_bounds__(BLOCK, 4) void ace_partial(const float* __restrict__ p,
                                                        const float* __restrict__ t,
                                                        float* __restrict__ partials,
                                                        int n4, int nblk) {
    const float K1 = K1f();
    const float K2 = K2f();

    // Pair bins: aW2[jp] = (sum w_{2jp}, sum w_{2jp+1}); packed fp32 (v_pk_*) halves j-loop ops.
    v2f aW2[NPAIR], aP2[NPAIR], aT2[NPAIR];
#pragma unroll
    for (int jp = 0; jp < NPAIR; ++jp) {
        aW2[jp] = (v2f){0.f, 0.f};
        aP2[jp] = (v2f){0.f, 0.f};
        aT2[jp] = (v2f){0.f, 0.f};
    }

    const float4* __restrict__ p4 = (const float4*)p;
    const float4* __restrict__ t4 = (const float4*)t;

    int tid    = blockIdx.x * BLOCK + threadIdx.x;
    int stride = gridDim.x * BLOCK;

    int i = tid;
    if (i < n4) {
        // software pipeline: loads for iteration k+1 issued before compute of k
        float4 pv = p4[i];
        float4 tv = t4[i];
        for (;;) {
            int inext = i + stride;
            bool more = (inext < n4);
            float4 pvn, tvn;
            if (more) { pvn = p4[inext]; tvn = t4[inext]; }

            float pe[4] = {pv.x, pv.y, pv.z, pv.w};
            float te[4] = {tv.x, tv.y, tv.z, tv.w};

#pragma unroll
            for (int e = 0; e < 4; ++e) {
                float pp = pe[e];
                float tt = te[e];
                float u  = __builtin_amdgcn_exp2f(K1 * pp * pp);  // exp(-p^2/T)
                float G  = __builtin_amdgcn_exp2f(K2 * pp);       // exp(2p/(19T))
                float GG = G * G;
                v2f g2;  g2.x = u;  g2.y = u * G;                 // (u*G^{2jp}, u*G^{2jp+1})
                v2f GG2 = (v2f){GG, GG};
                v2f pp2 = (v2f){pp, pp};
                v2f tt2 = (v2f){tt, tt};
#pragma unroll
                for (int jp = 0; jp < NPAIR; ++jp) {
                    aW2[jp] += g2;                                        // v_pk_add_f32
                    aP2[jp]  = __builtin_elementwise_fma(g2, pp2, aP2[jp]); // v_pk_fma_f32
                    aT2[jp]  = __builtin_elementwise_fma(g2, tt2, aT2[jp]); // v_pk_fma_f32
                    g2      *= GG2;                                       // v_pk_mul_f32
                }
            }

            if (!more) break;
            pv = pvn; tv = tvn; i = inext;
        }
    }

    // Wave(64)-level tree reduction of all 60 scalar accumulators
#pragma unroll
    for (int jp = 0; jp < NPAIR; ++jp) {
#pragma unroll
        for (int off = 32; off > 0; off >>= 1) {
            aW2[jp].x += __shfl_down(aW2[jp].x, off, 64);
            aW2[jp].y += __shfl_down(aW2[jp].y, off, 64);
            aP2[jp].x += __shfl_down(aP2[jp].x, off, 64);
            aP2[jp].y += __shfl_down(aP2[jp].y, off, 64);
            aT2[jp].x += __shfl_down(aT2[jp].x, off, 64);
            aT2[jp].y += __shfl_down(aT2[jp].y, off, 64);
        }
    }

    __shared__ float red[BLOCK / 64][NACC];
    int wave = threadIdx.x >> 6;
    int lane = threadIdx.x & 63;
    if (lane == 0) {
#pragma unroll
        for (int jp = 0; jp < NPAIR; ++jp) {
            red[wave][2 * jp]                    = aW2[jp].x;
            red[wave][2 * jp + 1]                = aW2[jp].y;
            red[wave][NUM_BINS + 2 * jp]         = aP2[jp].x;
            red[wave][NUM_BINS + 2 * jp + 1]     = aP2[jp].y;
            red[wave][2 * NUM_BINS + 2 * jp]     = aT2[jp].x;
            red[wave][2 * NUM_BINS + 2 * jp + 1] = aT2[jp].y;
        }
    }
    __syncthreads();

    // Transposed layout: partials[acc_idx * nblk + blockIdx.x] so the final kernel reads coalesced
    if (threadIdx.x < NACC) {
        float s = 0.f;
#pragma unroll
        for (int w = 0; w < BLOCK / 64; ++w) s += red[w][threadIdx.x];
        partials[threadIdx.x * nblk + blockIdx.x] = s;
    }
}

__global__ __launch_bounds__(1024) void ace_final(const float* __restrict__ partials,
                                                  float* __restrict__ out,
                                                  int nblk) {
    const float K1 = K1f();

    __shared__ float red[NACC][16];
    __shared__ float sums[NACC];
    int tid = threadIdx.x;

    if (tid < NACC * 16) {
        int j = tid >> 4;
        int k = tid & 15;
        float s = 0.f;
        // consecutive k -> consecutive b -> coalesced
        for (int b = k; b < nblk; b += 16) s += partials[j * nblk + b];
        red[j][k] = s;
    }
    __syncthreads();

    if (tid < NACC) {
        float s = 0.f;
#pragma unroll
        for (int k = 0; k < 16; ++k) s += red[tid][k];
        sums[tid] = s;
    }
    __syncthreads();

    if (tid == 0) {
        float acc = 0.f;
        for (int j = 0; j < NUM_BINS; ++j) {
            float c    = (float)j / 19.0f;
            float A    = __builtin_amdgcn_exp2f(K1 * c * c);  // exp(-c^2/T)
            float wsum = A * sums[j];
            float denom = wsum + 1e-8f;
            float e    = (A * sums[NUM_BINS + j]) / denom;
            float o    = (A * sums[2 * NUM_BINS + j]) / denom;
            float contrib = (wsum == 0.0f) ? 0.0f : fabsf(e - o);
            acc += contrib;
        }
        out[0] = acc / (float)NUM_BINS;
    }
}

extern "C" void kernel_launch(void* const* d_in, const int* in_sizes, int n_in,
                              void* d_out, int out_size, void* d_ws, size_t ws_size,
                              hipStream_t stream) {
    const float* preds   = (const float*)d_in[0];
    const float* targets = (const float*)d_in[1];
    float* out           = (float*)d_out;
    float* partials      = (float*)d_ws;

    int n  = in_sizes[0];
    int n4 = n >> 2;   // N = 32*1024*1024, divisible by 4

    int nblk = NBLK;
    size_t need = (size_t)nblk * NACC * sizeof(float);
    if (ws_size < need) {
        nblk = (int)(ws_size / (NACC * sizeof(float)));
        if (nblk < 1) nblk = 1;
    }

    ace_partial<<<nblk, BLOCK, 0, stream>>>(preds, targets, partials, n4, nblk);
    ace_final<<<1, 1024, 0, stream>>>(partials, out, nblk);
}